// Round 4
// baseline (226.629 us; speedup 1.0000x reference)
//
#include <hip/hip_runtime.h>

// ---------------------------------------------------------------------------
// NNSensorResponse: out[s,t] = sum_{b,n} sigmoid(MLPp(x))*MLPa(x)*mask * gauss(t-z)
// B=4,N=8000 (BN=32000), F_IN=3, HID=128, S=1024, T=1024, sigma runtime (=5.0).
// Gaussian band-limited (sigma=5 -> +-31 ticks): 16 buckets of 64-tick
// granularity, each owning a 128-tick span. Hp/Ha/GT stored in MFMA-fragment
// order, bucket-sorted; k_main stages Hp/Ha chunks to LDS, partial planes P,
// k_reduce sums <=8 contributors per out element.
// R12 (= R11 with the W2-shuffle OOB fixed): R11 crashed because the fused
// shuffle decoded kq over [0,32) with 64 ride-along blocks -- kq is only
// [0,16), so half the writes ran past WfP/WfA and clobbered meta/list ->
// k_main OOB -> abort. Now exactly 32 blocks, kq=(id>>10)&15, mat=id bit14.
// R11 content: (1) fuse count+scan+scatter into ONE single-block k_sort
// (per-wave LDS histograms; order within bucket irrelevant); W2 shuffle rides
// along (independent of sort). 5 kernels -> 4. (2) k_main: 2-chunk unroll per
// barrier (48 wave-MFMAs/barrier, 64KB dbuf LDS, 2 blk/CU), prefetch dist 2.
// (3) bucket-major XCD-chunked decode (bk=id&15: all 32 sharers of a bucket's
// ~1.5MB chunk data land on one XCD's L2).
// ---------------------------------------------------------------------------

#define BN_E   32000
#define HIDW   128
#define S_DIM  1024
#define T_DIM  1024
#define NBKT   16
#define KSPL   4
#define MAXPAD (BN_E + NBKT * 31)        // max padded list length (32496)
#define MAXCG  ((MAXPAD + 31) / 32)      // max 32-electron chunks (1016)
#define INV_SQRT_2PI 0.3989422804f

typedef __attribute__((ext_vector_type(8))) unsigned short u16x8;
typedef __attribute__((ext_vector_type(8))) __bf16         bf16x8;
typedef __attribute__((ext_vector_type(4))) float          f32x4;

static __device__ __forceinline__ unsigned short f2bf(float f) {
    union { float f; unsigned int u; } v; v.f = f;
    unsigned int r = v.u + 0x7FFFu + ((v.u >> 16) & 1u);   // RNE, inputs finite
    return (unsigned short)(r >> 16);
}

static __device__ __forceinline__ f32x4 mfma16(u16x8 a, u16x8 b, f32x4 c) {
    return __builtin_amdgcn_mfma_f32_16x16x32_bf16(
        __builtin_bit_cast(bf16x8, a), __builtin_bit_cast(bf16x8, b), c, 0, 0, 0);
}

static __device__ __forceinline__ int bucket_of(float z) {
    int b = (int)floorf((z - 31.f) * (1.f / 64.f));
    return min(max(b, 0), NBKT - 1);
}

// ---------------- fused sort (+ W2 shuffle riding along) --------------------
// block 0 (1024 thr): full bucket sort of 32000 electrons.
//   phase1: per-wave LDS histograms (contention only within wave).
//   scan:   cnt/pstart (padded to 32), publish meta; hist -> per-wave cursors.
//   phase2: scatter via LDS atomicAdd on per-wave cursors (order in bucket
//           irrelevant: the final reduction is commutative).
// blocks 1..32: W2 -> MFMA fragment order. 2 mats x 16 kq x 1024 s = 32768
//   threads. id = (bx-1)*1024+tid; mat = id bit14; kq = (id>>10)&15; s = tid.
__global__ __launch_bounds__(1024) void k_sort(
    const float* __restrict__ z,
    const float* __restrict__ Wp2, const float* __restrict__ Wa2,
    int* __restrict__ meta, int* __restrict__ list,
    unsigned short* __restrict__ WfP, unsigned short* __restrict__ WfA) {
    int bx = blockIdx.x, tid = threadIdx.x;
    if (bx > 0) {                                  // ---- W2 shuffle ----
        int id = (bx - 1) * 1024 + tid;            // 0..32767
        const float* src = (id & 16384) ? Wa2 : Wp2;
        unsigned short* dst = (id & 16384) ? WfA : WfP;
        int kq = (id >> 10) & 15;                  // ks*4+q, uniform per block
        int s  = tid;
        int ks = kq >> 2, q = kq & 3;
        unsigned short fr[8];
#pragma unroll
        for (int j = 0; j < 8; ++j)
            fr[j] = f2bf(src[(ks * 32 + q * 8 + j) * S_DIM + s]);
        ((u16x8*)dst)[kq * S_DIM + s] = *(u16x8*)fr;
        return;
    }
    // ---- sort ----
    __shared__ int hist[16][16];                   // [wave][bucket] -> cursors
    __shared__ int cntL[NBKT], pstartL[NBKT];
    int w = tid >> 6;
    if (tid < 256) ((int*)hist)[tid] = 0;
    __syncthreads();
    if (tid < 1000) {
#pragma unroll 4
        for (int i = 0; i < 32; ++i) {
            int e = i * 1000 + tid;                // 32*1000 = 32000 exactly
            atomicAdd(&hist[w][bucket_of(z[e])], 1);
        }
    }
    __syncthreads();
    if (tid < NBKT) {                              // cnt per bucket
        int s = 0;
#pragma unroll
        for (int w2 = 0; w2 < 16; ++w2) s += hist[w2][tid];
        cntL[tid] = s;
    }
    __syncthreads();
    if (tid == 0) {                                // padded prefix
        int s = 0;
        for (int i = 0; i < NBKT; ++i) {
            pstartL[i] = s;
            s += ((cntL[i] + 31) >> 5) << 5;
        }
        meta[48] = s;
    }
    __syncthreads();
    if (tid < NBKT) {
        meta[tid] = cntL[tid];
        meta[32 + tid] = pstartL[tid];
        int run = pstartL[tid];                    // hist -> per-wave base cursors
#pragma unroll
        for (int w2 = 0; w2 < 16; ++w2) { int h = hist[w2][tid]; hist[w2][tid] = run; run += h; }
    }
    __syncthreads();
    if (tid < 1000) {
#pragma unroll 4
        for (int i = 0; i < 32; ++i) {
            int e = i * 1000 + tid;
            int b = bucket_of(z[e]);
            int r = atomicAdd(&hist[w][b], 1);
            list[r] = e;
        }
    }
}

// ---------------- prep: fragment-ordered Hp/Ha/GT ---------------------------
// blocks [0, MAXCG): one per 32-electron sorted chunk.
//   Hp/Ha chunk (4096 shorts): unit u = kq*32 + e holds H[e][k=kq*8..+7].
//   GT chunk (4096 shorts): unit u=(n8*4+q)*16+c holds G[t=n8*16+c][e=q*8..+7].
__global__ __launch_bounds__(256) void k_prep(
    const float* __restrict__ x, const float* __restrict__ zg,
    const float* __restrict__ maskg, const float* __restrict__ sigp,
    const float* __restrict__ Wp1, const float* __restrict__ bp1,
    const float* __restrict__ Wa1, const float* __restrict__ ba1,
    const int* __restrict__ meta, const int* __restrict__ list,
    unsigned short* __restrict__ HpS, unsigned short* __restrict__ HaS,
    unsigned short* __restrict__ GT) {
    int bx = blockIdx.x;
    int tid = threadIdx.x;

    // W1/biases into LDS: [Wp1 384][bp1 128][Wa1 384][ba1 128] floats
    __shared__ float W1L[1024];
    __shared__ float zzL[32], cmL[32];
    __shared__ int metaL[33];    // [0..15]=cnt, [16..31]=pstart, [32]=total
    if (tid < 33) metaL[tid] = meta[tid < 16 ? tid : (tid < 32 ? tid + 16 : 48)];
    if (tid < 96)                        ((float4*)W1L)[tid]              = ((const float4*)Wp1)[tid];
    else if (tid < 128)                  ((float4*)(W1L + 384))[tid - 96] = ((const float4*)bp1)[tid - 96];
    else if (tid < 224)                  ((float4*)(W1L + 512))[tid - 128]= ((const float4*)Wa1)[tid - 128];
    else                                 ((float4*)(W1L + 896))[tid - 224]= ((const float4*)ba1)[tid - 224];
    __syncthreads();

    int pos0 = bx * 32;
    if (pos0 >= metaL[32]) return;
    int b = 15;
    while (metaL[16 + b] > pos0) --b;     // LDS search, chunk never crosses bucket
    int tb = b * 64, cnt = metaL[b], pstart = metaL[16 + b];

    if (tid < 32) {
        int pos = pos0 + tid;
        bool real = (pos - pstart) < cnt;
        int ev = real ? list[pos] : 0;
        float sigma = sigp[0];
        zzL[tid] = real ? zg[ev] : 0.f;
        cmL[tid] = real ? (INV_SQRT_2PI / sigma) * maskg[ev] : 0.f;
    }

    // ---- hidden states (fragment order, coalesced 512B store segments) ----
    {
        int e_l = tid & 31, part = tid >> 5;      // j = part*16 + i
        int pos = pos0 + e_l;
        bool real = (pos - pstart) < cnt;
        int ev = real ? list[pos] : 0;
        float x0 = 0.f, x1 = 0.f, x2 = 0.f;
        if (real) { x0 = x[ev * 3]; x1 = x[ev * 3 + 1]; x2 = x[ev * 3 + 2]; }
        unsigned short hp[16], ha[16];
#pragma unroll
        for (int i = 0; i < 16; ++i) {
            int j = part * 16 + i;
            float hv = x0 * W1L[j] + x1 * W1L[128 + j] + x2 * W1L[256 + j] + W1L[384 + j];
            float av = x0 * W1L[512 + j] + x1 * W1L[640 + j] + x2 * W1L[768 + j] + W1L[896 + j];
            hp[i] = real ? f2bf(fmaxf(hv, 0.f)) : (unsigned short)0;
            ha[i] = real ? f2bf(fmaxf(av, 0.f)) : (unsigned short)0;
        }
#pragma unroll
        for (int h2 = 0; h2 < 2; ++h2) {
            int u = (2 * part + h2) * 32 + e_l;   // kq = k0>>3 = 2*part+h2
            *(uint4*)&HpS[(size_t)bx * 4096 + u * 8] = ((uint4*)hp)[h2];
            *(uint4*)&HaS[(size_t)bx * 4096 + u * 8] = ((uint4*)ha)[h2];
        }
    }
    __syncthreads();   // zzL/cmL ready

    // ---- Gaussian tile (fragment order): 2 units x 8 electrons ----
    {
        float sigma = sigp[0];
        float nis2 = -1.f / (2.f * sigma * sigma);
#pragma unroll
        for (int uu = 0; uu < 2; ++uu) {
            int u = tid * 2 + uu;                 // 0..511
            int n8 = u >> 6, q = (u >> 4) & 3, c = u & 15;
            float tt = (float)(tb + n8 * 16 + c);
            unsigned short g8[8];
#pragma unroll
            for (int j = 0; j < 8; ++j) {
                int e = q * 8 + j;
                float d = tt - zzL[e];
                g8[j] = f2bf(cmL[e] * __expf(d * d * nis2));
            }
            *(uint4*)&GT[(size_t)bx * 4096 + u * 8] = *(uint4*)g8;
        }
    }
}

// ---------------- main fused kernel --------------------------------------
// grid: 512 linear blocks, 512 threads (8 waves), 2 blk/CU.
// Decode bk = id&15 -> bucket-major XCD chunking (id%8 = bk%8: all 32 blocks
// sharing a bucket's chunk data co-locate on one XCD's L2).
// 2-chunk unroll: stage 32KB (2 chunks of Hp+Ha) per barrier, double-buffered
// (64KB LDS); 48 wave-MFMAs between barriers; prefetch distance 2 chunks.
// Single barrier per iteration is safe: BAR_{k+1} separates any wave's buf
// reads (iter k) from any wave's buf rewrites (iter k+2).
__global__ __launch_bounds__(512, 4) void k_main(
    const unsigned short* __restrict__ HpS, const unsigned short* __restrict__ HaS,
    const unsigned short* __restrict__ WfP, const unsigned short* __restrict__ WfA,
    const float* __restrict__ bp2, const float* __restrict__ ba2,
    const int* __restrict__ meta, const unsigned short* __restrict__ GT,
    float* __restrict__ P) {

    const int id     = blockIdx.x;
    const int bk     = id & 15;
    const int kspl   = (id >> 4) & 3;
    const int y      = id >> 6;                // 0..7
    const int s0     = y * 128;
    const int cnt    = meta[bk];
    const int pstart = meta[32 + bk];          // padded, multiple of 32
    const int nch    = (cnt + 31) >> 5;
    const int per    = (nch + KSPL - 1) / KSPL;
    const int c0     = kspl * per;
    const int c1     = min(nch, c0 + per);

    const int tid = threadIdx.x;
    const int w = tid >> 6, l = tid & 63, q = l >> 4, c = l & 15;
    const f32x4 z4 = { 0.f, 0.f, 0.f, 0.f };
    float* Pp = P + (size_t)((bk * KSPL + kspl) * 8 + y) * 16384;

    if (c0 >= c1) {                            // uniform across block
        f32x4* p4 = (f32x4*)Pp;
#pragma unroll
        for (int i = 0; i < 8; ++i) p4[i * 512 + tid] = z4;
        return;
    }

    // LDS: double-buffered 2-chunk Hp/Ha stage (64 KB) + Rsp transpose (10 KB)
    __shared__ __align__(16) uint4 HpL[2048];
    __shared__ __align__(16) uint4 HaL[2048];
    __shared__ __align__(16) unsigned short RspL[128 * 40];

    // W2 fragments for this wave's 16 s-columns: 8 coalesced 16B loads.
    const u16x8* WfPv = (const u16x8*)WfP;
    const u16x8* WfAv = (const u16x8*)WfA;
    const int sg = s0 + w * 16 + c;
    u16x8 wP[4], wA[4];
#pragma unroll
    for (int ks = 0; ks < 4; ++ks) {
        wP[ks] = WfPv[(ks * 4 + q) * S_DIM + sg];
        wA[ks] = WfAv[(ks * 4 + q) * S_DIM + sg];
    }
    const float bp2v = bp2[sg];
    const float ba2v = ba2[sg];

    f32x4 acc2[8];
#pragma unroll
    for (int n8 = 0; n8 < 8; ++n8) acc2[n8] = z4;

    const uint4* Hp4 = (const uint4*)HpS;
    const uint4* Ha4 = (const uint4*)HaS;
    const int cgBase = pstart >> 5;            // first chunk index of bucket

    // one chunk's compute: GEMM1 -> epilogue1 -> GEMM2 (accumulates acc2)
    auto do_chunk = [&](int ci, const uint4* hpB, const uint4* haB) {
        // GT B-fragments direct from global (all 8 waves share -> L1 hot)
        const unsigned short* gt = GT + (size_t)(cgBase + ci) * 4096;
        u16x8 bfr[8];
#pragma unroll
        for (int n8 = 0; n8 < 8; ++n8)
            bfr[n8] = *(const u16x8*)&gt[((n8 * 4 + q) * 16 + c) * 8];

        // GEMM1: C1[e][s] = H[e][k] @ W2[k][s]  (M=e 32, N=s 16/wave, K=128)
        const u16x8* StHp = (const u16x8*)hpB;
        const u16x8* StHa = (const u16x8*)haB;
        f32x4 aP[2], aA[2];
        aP[0] = z4; aP[1] = z4; aA[0] = z4; aA[1] = z4;
#pragma unroll
        for (int ks = 0; ks < 4; ++ks) {
            u16x8 hp0 = StHp[(ks * 4 + q) * 32 + c];
            u16x8 hp1 = StHp[(ks * 4 + q) * 32 + c + 16];
            u16x8 ha0 = StHa[(ks * 4 + q) * 32 + c];
            u16x8 ha1 = StHa[(ks * 4 + q) * 32 + c + 16];
            aP[0] = mfma16(hp0, wP[ks], aP[0]);
            aP[1] = mfma16(hp1, wP[ks], aP[1]);
            aA[0] = mfma16(ha0, wA[ks], aA[0]);
            aA[1] = mfma16(ha1, wA[ks], aA[1]);
        }

        // epilogue1: rsp = sigmoid(p+bp2)*(a+ba2); C-layout -> RspL[s][e]
        // rows wave-private; DS ops in-order per wave -> no barrier needed
#pragma unroll
        for (int m = 0; m < 2; ++m) {
            f32x4 pp = aP[m], aa = aA[m];
            unsigned long long pk = 0;
#pragma unroll
            for (int r = 0; r < 4; ++r) {
                float pr = pp[r] + bp2v;
                float ar = aa[r] + ba2v;
                float sg2 = __builtin_amdgcn_rcpf(1.f + __expf(-pr));
                pk |= (unsigned long long)f2bf(sg2 * ar) << (16 * r);
            }
            *(unsigned long long*)&RspL[(w * 16 + c) * 40 + m * 16 + q * 4] = pk;
        }

        // GEMM2: out[s][t] += Rsp[s][e] @ G[e][t]  (M=s 16/wave, N=t 128, K=32)
        u16x8 afr = *(const u16x8*)&RspL[(w * 16 + c) * 40 + q * 8];
#pragma unroll
        for (int n8 = 0; n8 < 8; ++n8)
            acc2[n8] = mfma16(afr, bfr[n8], acc2[n8]);
    };

    // prefetch chunks c0, c0+1 (clamped; dup harmless)
    {
        size_t cbA = (size_t)(cgBase + c0) * 512;
        size_t cbB = (size_t)(cgBase + min(c0 + 1, c1 - 1)) * 512;
        uint4 pA = Hp4[cbA + tid], aA_ = Ha4[cbA + tid];
        uint4 pB = Hp4[cbB + tid], aB_ = Ha4[cbB + tid];

        for (int ci = c0; ci < c1; ci += 2) {
            const int buf = (((ci - c0) >> 1) & 1) << 10;  // 0 / 1024 uint4
            HpL[buf + tid] = pA; HpL[buf + 512 + tid] = pB;
            HaL[buf + tid] = aA_; HaL[buf + 512 + tid] = aB_;

            // issue next pair's prefetch (lands during this pair's compute)
            int n0 = min(ci + 2, c1 - 1), n1 = min(ci + 3, c1 - 1);
            size_t nbA = (size_t)(cgBase + n0) * 512;
            size_t nbB = (size_t)(cgBase + n1) * 512;
            pA = Hp4[nbA + tid]; aA_ = Ha4[nbA + tid];
            pB = Hp4[nbB + tid]; aB_ = Ha4[nbB + tid];
            __syncthreads();                   // staging of buf complete

            do_chunk(ci, HpL + buf, HaL + buf);
            if (ci + 1 < c1)
                do_chunk(ci + 1, HpL + buf + 512, HaL + buf + 512);
        }
    }

    // epilogue2: plain streaming stores to private partial plane.
#pragma unroll
    for (int n8 = 0; n8 < 8; ++n8) {
        int tl = n8 * 16 + c;
        int sl = w * 16 + q * 4;
#pragma unroll
        for (int r = 0; r < 4; ++r)
            Pp[(sl + r) * 128 + tl] = acc2[n8][r];
    }
}

// ---------------- reduce: out[s,t] = sum of <=8 partial contributions -------
// grid: 1024 x 256. thread -> one float4 of out (s = idx>>8, t0 = (idx&255)*4).
// Contributors: bucket bkA = t0>>6 (local col t0&63) and bkA-1 (col 64+(t0&63)),
// each x KSPL ksplit planes. All loads 16B coalesced; writes all of out.
__global__ __launch_bounds__(256) void k_reduce(const float* __restrict__ P,
                                                float* __restrict__ out) {
    int idx = blockIdx.x * 256 + threadIdx.x;     // 0..262143
    int t0  = (idx & 255) << 2;
    int s   = idx >> 8;
    int bkA = t0 >> 6;
    int colA = t0 & 63;
    int y    = s >> 7;
    int sl   = s & 127;
    const f32x4* P4 = (const f32x4*)P;
    f32x4 acc = { 0.f, 0.f, 0.f, 0.f };
#pragma unroll
    for (int k = 0; k < KSPL; ++k) {
        f32x4 v = P4[((size_t)(bkA * KSPL + k) * 8 + y) * 4096 + sl * 32 + (colA >> 2)];
        acc[0] += v[0]; acc[1] += v[1]; acc[2] += v[2]; acc[3] += v[3];
    }
    if (bkA > 0) {
        int colB = 64 + colA;
#pragma unroll
        for (int k = 0; k < KSPL; ++k) {
            f32x4 v = P4[((size_t)((bkA - 1) * KSPL + k) * 8 + y) * 4096 + sl * 32 + (colB >> 2)];
            acc[0] += v[0]; acc[1] += v[1]; acc[2] += v[2]; acc[3] += v[3];
        }
    }
    ((f32x4*)out)[idx] = acc;
}

// ---------------- launch ----------------

extern "C" void kernel_launch(void* const* d_in, const int* in_sizes, int n_in,
                              void* d_out, int out_size, void* d_ws, size_t ws_size,
                              hipStream_t stream) {
    const float* x    = (const float*)d_in[0];
    const float* zp   = (const float*)d_in[1];
    const float* mask = (const float*)d_in[2];
    const float* Wp1  = (const float*)d_in[3];
    const float* bp1  = (const float*)d_in[4];
    const float* Wp2  = (const float*)d_in[5];
    const float* bp2  = (const float*)d_in[6];
    const float* Wa1  = (const float*)d_in[7];
    const float* ba1  = (const float*)d_in[8];
    const float* Wa2  = (const float*)d_in[9];
    const float* ba2  = (const float*)d_in[10];
    const float* sig  = (const float*)d_in[11];

    char* ws = (char*)d_ws;
    unsigned short* HpS  = (unsigned short*)(ws);                      // 8,323,072 B
    unsigned short* HaS  = (unsigned short*)(ws + 8323072);            // 8,323,072 B
    unsigned short* WfP  = (unsigned short*)(ws + 16646144);           //   262,144 B
    unsigned short* WfA  = (unsigned short*)(ws + 16908288);           //   262,144 B
    int*            meta = (int*)(ws + 17170432);                      //       256 B
    int*            list = (int*)(ws + 17170688);                      //   130,048 B
    unsigned short* GT   = (unsigned short*)(ws + 17308736);           // 8,323,072 B
    float*          P    = (float*)(ws + 25631808);                    // 33,554,432 B
    // total ws ~59.2 MB

    k_sort<<<33, 1024, 0, stream>>>(zp, Wp2, Wa2, meta, list, WfP, WfA);
    k_prep<<<MAXCG, 256, 0, stream>>>(x, zp, mask, sig,
                                      Wp1, bp1, Wa1, ba1,
                                      meta, list, HpS, HaS, GT);
    k_main<<<512, 512, 0, stream>>>(
        HpS, HaS, WfP, WfA, bp2, ba2, meta, GT, P);
    k_reduce<<<1024, 256, 0, stream>>>(P, (float*)d_out);
}